// Round 13
// baseline (289.371 us; speedup 1.0000x reference)
//
#include <hip/hip_runtime.h>

// LSA_2147483648500: x[4,2048,1024](fp32) -> QKV proj -> 16-head attention
// (diag masked) -> out proj + bias. Internal bf16 MFMA; runtime dtype-detect.
//
// R19: gemm K-loop gets the 2-phase dbuf prefetch that fixed attn (R10->
// R11): old loop staged A/B then IMMEDIATELY barrier-drained them (1-phase,
// full gl2lds latency exposed every K-step; MfmaUtil 19%, ~1375cy/step vs
// 78cy MFMA). Now: lA/lB double-buffered (2x16KB), prologue stages t=0,
// loop = {issue stage(t+1) -> ds_read+MFMA(t) -> barrier}; the compiler's
// vmcnt(0)-before-s_barrier lands after the compute phase instead of
// before it (T3 minimum-2-phase; m230 2ph=682TF vs our ~570). Epilogue
// lC/lCf alias the dbuf (lCf stride 132->128 to fit) -> LDS=32KB both
// modes (MODE1 49.7->32.8KB, +1 blk/CU). attn (R11-exact), transpose_v,
// prep kernels, launcher frozen from R18 (285.7us best).

using u16 = unsigned short;
typedef short short8 __attribute__((ext_vector_type(8)));
typedef float floatx4 __attribute__((ext_vector_type(4)));
typedef float floatx16 __attribute__((ext_vector_type(16)));
typedef unsigned int uint2v __attribute__((ext_vector_type(2)));

#define B_ 4
#define N_ 2048
#define H_ 16
#define DH_ 64
#define D_ 1024
#define INNER_ 1024
#define M_ (B_ * N_)   // 8192

__device__ __forceinline__ float bf2f(u16 h) {
    union { unsigned u; float f; } c; c.u = ((unsigned)h) << 16; return c.f;
}
__device__ __forceinline__ u16 f2bf(float f) {
    union { float f; unsigned u; } c; c.f = f;
    unsigned u = c.u + 0x7fffu + ((c.u >> 16) & 1u);
    return (u16)(u >> 16);
}
__device__ __forceinline__ unsigned cvtpk_bf16(float lo, float hi) {
    unsigned r;
    asm("v_cvt_pk_bf16_f32 %0, %1, %2" : "=v"(r) : "v"(lo), "v"(hi));
    return r;
}
__device__ __forceinline__ float fast_exp2(float x) {
#if defined(__has_builtin) && __has_builtin(__builtin_amdgcn_exp2f)
    return __builtin_amdgcn_exp2f(x);
#else
    return __expf(x * 0.69314718056f);
#endif
}
__device__ __forceinline__ void gl2lds16(const u16* g, u16* l) {
    __builtin_amdgcn_global_load_lds(
        (const __attribute__((address_space(1))) void*)g,
        (__attribute__((address_space(3))) void*)l, 16, 0, 0);
}

// -------- detect dtype + bias/temperature prep (one block) -----------------
__global__ void detect_prep(const u16* __restrict__ x, int* __restrict__ flag,
                            const void* __restrict__ bias_in,
                            const void* __restrict__ temp_in,
                            float* __restrict__ bias_f,
                            float* __restrict__ temp_f) {
    __shared__ int cnt;
    __shared__ int fl;
    if (threadIdx.x == 0) cnt = 0;
    __syncthreads();
    int c = 0;
    for (int i = threadIdx.x; i < 4096; i += 256) {
        int e = (x[i] >> 7) & 0xFF;
        if (e >= 107 && e <= 147) c++;
    }
    atomicAdd(&cnt, c);
    __syncthreads();
    if (threadIdx.x == 0) { fl = (cnt >= 3584) ? 1 : 0; flag[0] = fl; }
    __syncthreads();
    const int f = fl;
    for (int i = threadIdx.x; i < 1024; i += 256)
        bias_f[i] = f ? bf2f(((const u16*)bias_in)[i]) : ((const float*)bias_in)[i];
    if (threadIdx.x == 0)
        temp_f[0] = f ? bf2f(((const u16*)temp_in)[0]) : ((const float*)temp_in)[0];
}

// -------- fused input prep: convert x + transpose Wqkv + transpose Wout ----
// grid.x = 4096 (convert) + 3072 (Wqkv tcvt 96x32) + 1024 (Wout tcvt 32x32)
__global__ __launch_bounds__(256) void prep_inputs(
    const void* __restrict__ x, u16* __restrict__ xb,
    const void* __restrict__ Wqkv, u16* __restrict__ Wqkv_t,
    const void* __restrict__ Wout, u16* __restrict__ Wout_t,
    const int* __restrict__ flag) {
    __shared__ u16 t[32][33];
    const int f = flag[0];
    const int b = blockIdx.x;
    if (b < 4096) {
        long i0 = ((long)b * 256 + threadIdx.x) * 8;
        u16 tmp[8];
        if (f) {
            *(short8*)tmp = *(const short8*)((const u16*)x + i0);
        } else {
            const float* p = (const float*)x + i0;
            for (int i = 0; i < 8; i++) tmp[i] = f2bf(p[i]);
        }
        *(short8*)&xb[i0] = *(const short8*)tmp;
        return;
    }
    const void* in;
    u16* out;
    int bx, by, R, C;
    if (b < 4096 + 3072) {
        int idx = b - 4096;
        bx = idx % 96; by = idx / 96; R = D_; C = 3 * INNER_;
        in = Wqkv; out = Wqkv_t;
    } else {
        int idx = b - 7168;
        bx = idx % 32; by = idx / 32; R = INNER_; C = D_;
        in = Wout; out = Wout_t;
    }
    int tx = threadIdx.x & 31, ty = threadIdx.x >> 5;
    int c0 = bx * 32, r0 = by * 32;
    for (int i = 0; i < 4; i++) {
        long idx = (long)(r0 + ty + i * 8) * C + c0 + tx;
        t[ty + i * 8][tx] = f ? ((const u16*)in)[idx] : f2bf(((const float*)in)[idx]);
    }
    __syncthreads();
    for (int i = 0; i < 4; i++)
        out[(long)(c0 + ty + i * 8) * R + r0 + tx] = t[tx][ty + i * 8];
}

// -------- transpose v: per-bh [N][64] -> [64][N], bf16 ----------------------
__global__ __launch_bounds__(256) void transpose_v(
    const u16* __restrict__ in, u16* __restrict__ out) {
    __shared__ u16 t[32][33];
    const int bh = blockIdx.z;
    const u16* src = in + (long)bh * N_ * DH_;
    u16* dst = out + (long)bh * DH_ * N_;
    int tx = threadIdx.x & 31, ty = threadIdx.x >> 5;
    int r0 = blockIdx.y * 32;   // n rows
    int c0 = blockIdx.x * 32;   // dh cols
    for (int i = 0; i < 4; i++)
        t[ty + i * 8][tx] = src[(long)(r0 + ty + i * 8) * DH_ + c0 + tx];
    __syncthreads();
    for (int i = 0; i < 4; i++)
        dst[(long)(c0 + ty + i * 8) * N_ + r0 + tx] = t[tx][ty + i * 8];
}

// ---------------- GEMM: C[M,N] = A[M,K] * Bt[N,K]^T, bf16 MFMA --------------
// 128x128 tile, BK=32, 4 waves 2x2, swizzled LDS via source-permuted
// global_load_lds. K-loop 2-phase double-buffered: stage(t+1) issues
// BEFORE compute(t); single barrier per K-step drains the prefetch AFTER
// the MFMA phase covered its latency. Epilogue buffers alias the dbuf.
// Default block mapping (m-tile fastest -> per-XCD A-residency).
// MODE 0: LDS-staged coalesced scatter to q (pre-scaled), k, v.
// MODE 1: +bias, LDS-staged coalesced nt-store (d_out never re-read).
template <int MODE>
__global__ __launch_bounds__(256) void gemm_bt(
    const u16* __restrict__ A, const u16* __restrict__ Bt,
    int M, int N, int K,
    u16* __restrict__ out0, u16* __restrict__ out1, u16* __restrict__ out2,
    void* __restrict__ outv, const float* __restrict__ bias,
    const int* __restrict__ flag, const float* __restrict__ temp_f) {
    // 32 KB: two (lA|lB) buffers; epilogue lC/lCf alias this region.
    __shared__ __align__(16) u16 smem[16384];
    const int tid = threadIdx.x;
    const int lane = tid & 63;
    const int w = tid >> 6;
    const int wr = w >> 1, wc = w & 1;
    const int qd = lane >> 4, qm = lane & 15;
    const long m0 = (long)blockIdx.x * 128;
    const long n0 = (long)blockIdx.y * 128;

    floatx4 acc[4][4];
    for (int i = 0; i < 4; i++)
        for (int j = 0; j < 4; j++) acc[i][j] = (floatx4){0.f, 0.f, 0.f, 0.f};

    const int arow = lane >> 2;
    const int acol = ((lane & 3) ^ ((lane >> 3) & 3)) * 8;
    const int swz = (qm >> 1) & 3;

    // prologue: stage k=0 into buffer 0
    {
        u16* lA = smem;
        u16* lB = smem + 4096;
        for (int i = 0; i < 2; i++) {
            int c = w + i * 4;
            gl2lds16(A + (m0 + c * 16 + arow) * K + acol, lA + c * 512);
            gl2lds16(Bt + (n0 + c * 16 + arow) * K + acol, lB + c * 512);
        }
    }
    __syncthreads();

    const int nT = K >> 5;
    for (int t = 0; t < nT; ++t) {
        const u16* lA = smem + (t & 1) * 8192;
        const u16* lB = lA + 4096;
        // prefetch next K-step into the other buffer (read last at t-1;
        // barrier at end of t-1 protects). Drained by end-of-t barrier,
        // AFTER the MFMA phase below has covered the latency.
        if (t + 1 < nT) {
            u16* nA = smem + ((t + 1) & 1) * 8192;
            u16* nB = nA + 4096;
            const int k1 = (t + 1) << 5;
            for (int i = 0; i < 2; i++) {
                int c = w + i * 4;
                gl2lds16(A + (m0 + c * 16 + arow) * K + k1 + acol, nA + c * 512);
                gl2lds16(Bt + (n0 + c * 16 + arow) * K + k1 + acol, nB + c * 512);
            }
        }
        short8 af[4], bfr[4];
        for (int mt = 0; mt < 4; mt++)
            af[mt] = *(const short8*)&lA[(wr * 64 + mt * 16 + qm) * 32 + (qd ^ swz) * 8];
        for (int nt = 0; nt < 4; nt++)
            bfr[nt] = *(const short8*)&lB[(wc * 64 + nt * 16 + qm) * 32 + (qd ^ swz) * 8];
        for (int mt = 0; mt < 4; mt++)
            for (int nt = 0; nt < 4; nt++)
                acc[mt][nt] = __builtin_amdgcn_mfma_f32_16x16x32_bf16(
                    af[mt], bfr[nt], acc[mt][nt], 0, 0, 0);
        __syncthreads();
    }

    if (MODE == 0) {
        // LDS-staged epilogue (lC aliases smem: 8448 u16 <= 16384): two
        // 64-row halves; each 128B output line written once, fully.
        const float qscale = __expf(temp_f[0]) * 1.44269504089f;
        u16* lC = smem;
        for (int half = 0; half < 2; half++) {
            __syncthreads();
            if (wr == half) {
                for (int nt = 0; nt < 4; nt++) {
                    long ng = n0 + wc * 64 + nt * 16 + qm;
                    float sc = ((ng >> 10) == 0) ? qscale : 1.0f;
                    for (int mt = 0; mt < 4; mt++)
                        for (int r = 0; r < 4; r++)
                            lC[(mt * 16 + qd * 4 + r) * 132 + wc * 64 + nt * 16 + qm] =
                                f2bf(acc[mt][nt][r] * sc);
                }
            }
            __syncthreads();
            for (int i = 0; i < 4; i++) {
                int row = (tid >> 4) + i * 16;       // 0..63
                int c = (tid & 15) * 8;              // col, 8-aligned
                long m = m0 + half * 64 + row;
                long ngc = n0 + c;
                int part = (int)(ngc >> 10);
                int rem = (int)(ngc & 1023);
                int hh = rem >> 6, dh = rem & 63;
                long bb = m >> 11, n = m & 2047;
                long idx = ((bb * H_ + hh) * N_ + n) * DH_ + dh;
                short8 vv = *(const short8*)&lC[row * 132 + c];
                u16* dst = (part == 0) ? out0 : (part == 1) ? out1 : out2;
                *(short8*)&dst[idx] = vv;
            }
        }
    } else {
        // LDS-staged fp32 epilogue (lCf aliases smem; stride 128 dwords so
        // 64*128 floats = 32KB fits exactly), cooperative full-line nt
        // stores (d_out never re-read by any later kernel).
        const int f = flag[0];
        float* lCf = (float*)smem;
        for (int half = 0; half < 2; half++) {
            __syncthreads();
            if (wr == half) {
                for (int nt = 0; nt < 4; nt++) {
                    long ng = n0 + wc * 64 + nt * 16 + qm;
                    float bv = bias[ng];
                    for (int mt = 0; mt < 4; mt++)
                        for (int r = 0; r < 4; r++)
                            lCf[(mt * 16 + qd * 4 + r) * 128 + wc * 64 + nt * 16 + qm] =
                                acc[mt][nt][r] + bv;
                }
            }
            __syncthreads();
            if (f) {
                for (int i = 0; i < 4; i++) {
                    int row = (tid >> 4) + i * 16;   // 0..63
                    int c = (tid & 15) * 8;          // col, 8-aligned
                    long m = m0 + half * 64 + row;
                    u16 tmp[8];
                    for (int j = 0; j < 8; j++) tmp[j] = f2bf(lCf[row * 128 + c + j]);
                    __builtin_nontemporal_store(*(const short8*)tmp,
                        (short8*)&((u16*)outv)[m * N + n0 + c]);
                }
            } else {
                for (int i = 0; i < 8; i++) {
                    int row = (tid >> 5) + i * 8;    // 0..63
                    int c = (tid & 31) * 4;          // col, 4-aligned fp32
                    long m = m0 + half * 64 + row;
                    floatx4 vv = *(const floatx4*)&lCf[row * 128 + c];
                    __builtin_nontemporal_store(vv,
                        (floatx4*)&((float*)outv)[m * N + n0 + c]);
                }
            }
        }
    }
}

// ---------------- flash attention, R11-exact -------------------------------
// grid = (8, 64) remapped XCD-aware; 512 blocks x 4 waves (2 blocks/CU).
// Wave w owns qrows qbase..+63 as 2 groups of 32; each K/V fragment read
// feeds both groups' MFMAs. K/V double-buffered. S^T = K*Q^T via
// mfma_32x32x16; P->bf16 cvt_pk; permlane32_swap builds PV B-frag; 1/l
// lane-local. Output LDS-staged full-line stores.
__global__ __launch_bounds__(256) void attn_full(
    const u16* __restrict__ q_ws, const u16* __restrict__ k_ws,
    const u16* __restrict__ vt_ws, u16* __restrict__ out) {
    __shared__ __align__(16) u16 lbuf[2 * 2 * 64 * 64];  // 32 KiB
    const int tid = threadIdx.x, lane = tid & 63, w = tid >> 6;
    const int ln = lane & 31, h = lane >> 5;

    int linear = blockIdx.y * 8 + blockIdx.x;
    int bh = (linear & 7) * 8 + ((linear >> 6) & 7);
    int q0 = ((linear >> 3) & 7) * 256;
    const int b = bh >> 4, hd = bh & 15;

    const u16* Q = q_ws + (long)bh * N_ * DH_;
    const u16* Kp = k_ws + (long)bh * N_ * DH_;
    const u16* Vt = vt_ws + (long)bh * DH_ * N_;

    const int qbase = q0 + w * 64;

    short8 qa[2][4];
#pragma unroll
    for (int g = 0; g < 2; g++)
#pragma unroll
        for (int c = 0; c < 4; c++)
            qa[g][c] = *(const short8*)
                &Q[(long)(qbase + g * 32 + ln) * DH_ + c * 16 + h * 8];

    floatx16 accO[2][2];
#pragma unroll
    for (int i = 0; i < 16; i++) {
        accO[0][0][i] = 0.f; accO[0][1][i] = 0.f;
        accO[1][0][i] = 0.f; accO[1][1][i] = 0.f;
    }
    float lacc[2] = {0.f, 0.f};

    const int srow = lane >> 3;
    const int scol = ((lane & 7) ^ srow) * 8;
    const int rsw = (ln & 7);

    {
        u16* nK = lbuf;
        u16* nV = lbuf + 4096;
        for (int i = 0; i < 2; i++) {
            int c = w + i * 4;
            gl2lds16(Kp + (long)(c * 8 + srow) * DH_ + scol, nK + c * 512);
            gl2lds16(Vt + (long)(c * 8 + srow) * N_ + scol, nV + c * 512);
        }
    }
    __syncthreads();

    for (int t = 0; t < 32; t++) {
        const int k0 = t * 64;
        const u16* lK = lbuf + (t & 1) * 8192;
        const u16* lV = lK + 4096;
        if (t < 31) {
            u16* nK = lbuf + ((t + 1) & 1) * 8192;
            u16* nV = nK + 4096;
            for (int i = 0; i < 2; i++) {
                int c = w + i * 4;
                gl2lds16(Kp + (long)(k0 + 64 + c * 8 + srow) * DH_ + scol,
                         nK + c * 512);
                gl2lds16(Vt + (long)(c * 8 + srow) * N_ + k0 + 64 + scol,
                         nV + c * 512);
            }
        }

#pragma unroll
        for (int kt = 0; kt < 2; kt++) {
            floatx16 accS[2];
#pragma unroll
            for (int i = 0; i < 16; i++) { accS[0][i] = 0.f; accS[1][i] = 0.f; }
#pragma unroll
            for (int c = 0; c < 4; c++) {
                short8 kf = *(const short8*)
                    &lK[(kt * 32 + ln) * 64 + ((c * 2 + h) ^ rsw) * 8];
                accS[0] = __builtin_amdgcn_mfma_f32_32x32x16_bf16(
                    kf, qa[0][c], accS[0], 0, 0, 0);
                accS[1] = __builtin_amdgcn_mfma_f32_32x32x16_bf16(
                    kf, qa[1][c], accS[1], 0, 0, 0);
            }
#pragma unroll
            for (int g = 0; g < 2; g++) {
#pragma unroll
                for (int r = 0; r < 16; r++)
                    accS[g][r] = fast_exp2(accS[g][r]);
                if ((qbase + g * 32) == (k0 + kt * 32)) {
#pragma unroll
                    for (int r = 0; r < 16; r++) {
                        int kk = (r & 3) + 8 * (r >> 2) + 4 * h;
                        if (kk == ln) accS[g][r] = 0.f;
                    }
                }
                float rs = (((accS[g][0] + accS[g][1]) + (accS[g][2] + accS[g][3]))
                          + ((accS[g][4] + accS[g][5]) + (accS[g][6] + accS[g][7])))
                         + (((accS[g][8] + accS[g][9]) + (accS[g][10] + accS[g][11]))
                          + ((accS[g][12] + accS[g][13]) + (accS[g][14] + accS[g][15])));
                lacc[g] += rs;
            }
#pragma unroll
            for (int ch = 0; ch < 2; ch++) {
                const int rb = ch * 8;
                short8 pfv[2];
#pragma unroll
                for (int g = 0; g < 2; g++) {
                    unsigned d01 = cvtpk_bf16(accS[g][rb + 0], accS[g][rb + 1]);
                    unsigned d23 = cvtpk_bf16(accS[g][rb + 2], accS[g][rb + 3]);
                    unsigned d45 = cvtpk_bf16(accS[g][rb + 4], accS[g][rb + 5]);
                    unsigned d67 = cvtpk_bf16(accS[g][rb + 6], accS[g][rb + 7]);
                    uint2v s1 = __builtin_amdgcn_permlane32_swap(d01, d45, false, false);
                    uint2v s2 = __builtin_amdgcn_permlane32_swap(d23, d67, false, false);
                    union { unsigned u[4]; short8 v; } pf;
                    pf.u[0] = s1[0]; pf.u[1] = s2[0]; pf.u[2] = s1[1]; pf.u[3] = s2[1];
                    pfv[g] = pf.v;
                }
                const int cc = kt * 2 + ch;
#pragma unroll
                for (int dt = 0; dt < 2; dt++) {
                    short8 vf = *(const short8*)
                        &lV[(dt * 32 + ln) * 64 + ((cc * 2 + h) ^ rsw) * 8];
                    accO[0][dt] = __builtin_amdgcn_mfma_f32_32x32x16_bf16(
                        vf, pfv[0], accO[0][dt], 0, 0, 0);
                    accO[1][dt] = __builtin_amdgcn_mfma_f32_32x32x16_bf16(
                        vf, pfv[1], accO[1][dt], 0, 0, 0);
                }
            }
        }
        __syncthreads();
    }

#pragma unroll
    for (int g = 0; g < 2; g++) {
        float s = lacc[g];
        s += __shfl_xor(s, 32, 64);
        const float inv = 1.f / s;
        u16* stg = (u16*)((char*)lbuf + w * 8192 + g * 4096);
#pragma unroll
        for (int dt = 0; dt < 2; dt++)
#pragma unroll
            for (int q2 = 0; q2 < 4; q2++) {
                union { unsigned u[2]; unsigned long long ull; } ee;
                ee.u[0] = cvtpk_bf16(accO[g][dt][q2 * 4 + 0] * inv,
                                     accO[g][dt][q2 * 4 + 1] * inv);
                ee.u[1] = cvtpk_bf16(accO[g][dt][q2 * 4 + 2] * inv,
                                     accO[g][dt][q2 * 4 + 3] * inv);
                int G = dt * 4 + q2;
                *(unsigned long long*)
                    &stg[ln * 64 + ((G ^ rsw) * 8) + h * 4] = ee.ull;
            }
    }
    __syncthreads();
#pragma unroll
    for (int p = 0; p < 8; p++) {
        int R = p * 32 + (tid >> 3);
        int G = tid & 7;
        const u16* src = (const u16*)((char*)lbuf + (R >> 6) * 8192
                          + ((R >> 5) & 1) * 4096
                          + (R & 31) * 128 + ((G ^ (R & 7)) * 16));
        short8 vv = *(const short8*)src;
        *(short8*)&out[((long)(b * N_ + q0 + R)) * INNER_ + hd * DH_ + G * 8] = vv;
    }
}

extern "C" void kernel_launch(void* const* d_in, const int* in_sizes, int n_in,
                              void* d_out, int out_size, void* d_ws, size_t ws_size,
                              hipStream_t stream) {
    const void* x    = d_in[0];
    const void* Wqkv = d_in[1];
    const void* Wout = d_in[2];
    const void* bout = d_in[3];
    const void* temp = d_in[4];

    char* base = (char*)d_ws;
    int*   flag    = (int*)base;
    float* temp_f  = (float*)(base + 16);
    float* bias_f  = (float*)(base + 32);
    u16* xb      = (u16*)(base + 8192);
    u16* Wqkv_t  = xb + (long)M_ * D_;
    u16* Wout_t  = Wqkv_t + 3072 * 1024;
    u16* q_ws    = Wout_t + 1024 * 1024;
    u16* k_ws    = q_ws + (long)B_ * H_ * N_ * DH_;
    u16* vt_ws   = k_ws + (long)B_ * H_ * N_ * DH_;
    u16* attn_out = vt_ws + (long)B_ * H_ * N_ * DH_;
    u16* v_nat   = attn_out;  // alias: dead until attn_full writes it

    dim3 blk(256);
    detect_prep<<<1, blk, 0, stream>>>((const u16*)x, flag, bout, temp,
                                       bias_f, temp_f);
    prep_inputs<<<dim3(4096 + 3072 + 1024), blk, 0, stream>>>(
        x, xb, Wqkv, Wqkv_t, Wout, Wout_t, flag);
    gemm_bt<0><<<dim3(M_ / 128, 3 * INNER_ / 128), blk, 0, stream>>>(
        xb, Wqkv_t, M_, 3 * INNER_, D_, q_ws, k_ws, v_nat, nullptr, nullptr,
        flag, temp_f);
    transpose_v<<<dim3(DH_ / 32, N_ / 32, B_ * H_), blk, 0, stream>>>(
        v_nat, vt_ws);
    attn_full<<<dim3(8, 64), blk, 0, stream>>>(
        q_ws, k_ws, vt_ws, attn_out);
    gemm_bt<1><<<dim3(M_ / 128, D_ / 128), blk, 0, stream>>>(
        attn_out, Wout_t, M_, D_, INNER_, nullptr, nullptr, nullptr, d_out,
        bias_f, flag, temp_f);
}

// Round 14
// 276.707 us; speedup vs baseline: 1.0458x; 1.0458x over previous
//
#include <hip/hip_runtime.h>

// LSA_2147483648500: x[4,2048,1024](fp32) -> QKV proj -> 16-head attention
// (diag masked) -> out proj + bias. Internal bf16 MFMA; runtime dtype-detect.
//
// R20: R19's 2-phase dbuf at 128x128/BK32 was NULL — documented (m99/m100):
// at 2-3 blocks/CU, implicit wave overlap already covers the drain; dbuf
// redundant. The distinguishing knobs are per-barrier compute mass and
// grid shape. gemm rewritten: BM=128 x BN=256 x BK=64, 512 thr (8 waves
// 2x4, 64x64 out/wave), 2-phase dbuf, LDS 96KB (1 blk/CU): 16 K-tiles
// (half the barriers), 32 MFMA + 16 ds_read/wave per barrier (~350cy
// cover vs ~80), grid 768/256 = exactly 3/1 full CU-waves (no tail).
// Same per-row-XOR granule swizzle (stage LDS[r][g]=glob[r][g^(r&7)],
// read XORs back); same two-half LDS-staged epilogues widened to 256
// cols (tiles never span a qkv part: 1024%256=0). attn (R11-exact),
// transpose_v, prep kernels frozen from R18 (285.7us best).

using u16 = unsigned short;
typedef short short8 __attribute__((ext_vector_type(8)));
typedef float floatx4 __attribute__((ext_vector_type(4)));
typedef float floatx16 __attribute__((ext_vector_type(16)));
typedef unsigned int uint2v __attribute__((ext_vector_type(2)));

#define B_ 4
#define N_ 2048
#define H_ 16
#define DH_ 64
#define D_ 1024
#define INNER_ 1024
#define M_ (B_ * N_)   // 8192

__device__ __forceinline__ float bf2f(u16 h) {
    union { unsigned u; float f; } c; c.u = ((unsigned)h) << 16; return c.f;
}
__device__ __forceinline__ u16 f2bf(float f) {
    union { float f; unsigned u; } c; c.f = f;
    unsigned u = c.u + 0x7fffu + ((c.u >> 16) & 1u);
    return (u16)(u >> 16);
}
__device__ __forceinline__ unsigned cvtpk_bf16(float lo, float hi) {
    unsigned r;
    asm("v_cvt_pk_bf16_f32 %0, %1, %2" : "=v"(r) : "v"(lo), "v"(hi));
    return r;
}
__device__ __forceinline__ float fast_exp2(float x) {
#if defined(__has_builtin) && __has_builtin(__builtin_amdgcn_exp2f)
    return __builtin_amdgcn_exp2f(x);
#else
    return __expf(x * 0.69314718056f);
#endif
}
__device__ __forceinline__ void gl2lds16(const u16* g, u16* l) {
    __builtin_amdgcn_global_load_lds(
        (const __attribute__((address_space(1))) void*)g,
        (__attribute__((address_space(3))) void*)l, 16, 0, 0);
}

// -------- detect dtype + bias/temperature prep (one block) -----------------
__global__ void detect_prep(const u16* __restrict__ x, int* __restrict__ flag,
                            const void* __restrict__ bias_in,
                            const void* __restrict__ temp_in,
                            float* __restrict__ bias_f,
                            float* __restrict__ temp_f) {
    __shared__ int cnt;
    __shared__ int fl;
    if (threadIdx.x == 0) cnt = 0;
    __syncthreads();
    int c = 0;
    for (int i = threadIdx.x; i < 4096; i += 256) {
        int e = (x[i] >> 7) & 0xFF;
        if (e >= 107 && e <= 147) c++;
    }
    atomicAdd(&cnt, c);
    __syncthreads();
    if (threadIdx.x == 0) { fl = (cnt >= 3584) ? 1 : 0; flag[0] = fl; }
    __syncthreads();
    const int f = fl;
    for (int i = threadIdx.x; i < 1024; i += 256)
        bias_f[i] = f ? bf2f(((const u16*)bias_in)[i]) : ((const float*)bias_in)[i];
    if (threadIdx.x == 0)
        temp_f[0] = f ? bf2f(((const u16*)temp_in)[0]) : ((const float*)temp_in)[0];
}

// -------- fused input prep: convert x + transpose Wqkv + transpose Wout ----
// grid.x = 4096 (convert) + 3072 (Wqkv tcvt 96x32) + 1024 (Wout tcvt 32x32)
__global__ __launch_bounds__(256) void prep_inputs(
    const void* __restrict__ x, u16* __restrict__ xb,
    const void* __restrict__ Wqkv, u16* __restrict__ Wqkv_t,
    const void* __restrict__ Wout, u16* __restrict__ Wout_t,
    const int* __restrict__ flag) {
    __shared__ u16 t[32][33];
    const int f = flag[0];
    const int b = blockIdx.x;
    if (b < 4096) {
        long i0 = ((long)b * 256 + threadIdx.x) * 8;
        u16 tmp[8];
        if (f) {
            *(short8*)tmp = *(const short8*)((const u16*)x + i0);
        } else {
            const float* p = (const float*)x + i0;
            for (int i = 0; i < 8; i++) tmp[i] = f2bf(p[i]);
        }
        *(short8*)&xb[i0] = *(const short8*)tmp;
        return;
    }
    const void* in;
    u16* out;
    int bx, by, R, C;
    if (b < 4096 + 3072) {
        int idx = b - 4096;
        bx = idx % 96; by = idx / 96; R = D_; C = 3 * INNER_;
        in = Wqkv; out = Wqkv_t;
    } else {
        int idx = b - 7168;
        bx = idx % 32; by = idx / 32; R = INNER_; C = D_;
        in = Wout; out = Wout_t;
    }
    int tx = threadIdx.x & 31, ty = threadIdx.x >> 5;
    int c0 = bx * 32, r0 = by * 32;
    for (int i = 0; i < 4; i++) {
        long idx = (long)(r0 + ty + i * 8) * C + c0 + tx;
        t[ty + i * 8][tx] = f ? ((const u16*)in)[idx] : f2bf(((const float*)in)[idx]);
    }
    __syncthreads();
    for (int i = 0; i < 4; i++)
        out[(long)(c0 + ty + i * 8) * R + r0 + tx] = t[tx][ty + i * 8];
}

// -------- transpose v: per-bh [N][64] -> [64][N], bf16 ----------------------
__global__ __launch_bounds__(256) void transpose_v(
    const u16* __restrict__ in, u16* __restrict__ out) {
    __shared__ u16 t[32][33];
    const int bh = blockIdx.z;
    const u16* src = in + (long)bh * N_ * DH_;
    u16* dst = out + (long)bh * DH_ * N_;
    int tx = threadIdx.x & 31, ty = threadIdx.x >> 5;
    int r0 = blockIdx.y * 32;   // n rows
    int c0 = blockIdx.x * 32;   // dh cols
    for (int i = 0; i < 4; i++)
        t[ty + i * 8][tx] = src[(long)(r0 + ty + i * 8) * DH_ + c0 + tx];
    __syncthreads();
    for (int i = 0; i < 4; i++)
        dst[(long)(c0 + ty + i * 8) * N_ + r0 + tx] = t[tx][ty + i * 8];
}

// ---------------- GEMM: C[M,N] = A[M,K] * Bt[N,K]^T, bf16 MFMA --------------
// 128x256 tile, BK=64, 512 thr = 8 waves (2x4), 64x64 out/wave, 2-phase
// dbuf (prefetch t+1 issued before compute t; one barrier per K-tile).
// LDS 96KB = 2 x (A 16KB + B 32KB); epilogues alias it. Staging puts
// LDS[r][g] = global[r][g ^ (r&7)] (per-row granule XOR); frag reads XOR
// back -> 2-way banks (free). Default block mapping (m fastest).
// MODE 0: two-half LDS-staged scatter to q (pre-scaled), k, v [BH][N][DH].
// MODE 1: +bias, two-half LDS-staged nt-store (d_out never re-read).
template <int MODE>
__global__ __launch_bounds__(512) void gemm_bt(
    const u16* __restrict__ A, const u16* __restrict__ Bt,
    int M, int N, int K,
    u16* __restrict__ out0, u16* __restrict__ out1, u16* __restrict__ out2,
    void* __restrict__ outv, const float* __restrict__ bias,
    const int* __restrict__ flag, const float* __restrict__ temp_f) {
    __shared__ __align__(16) u16 smem[49152];   // 96 KB
    const int tid = threadIdx.x;
    const int lane = tid & 63;
    const int w = tid >> 6;              // 0..7
    const int wm = w >> 2, wn = w & 3;   // 2 x 4 wave grid
    const int qd = lane >> 4, qm = lane & 15;
    const long m0 = (long)blockIdx.x * 128;
    const long n0 = (long)blockIdx.y * 256;

    floatx4 acc[4][4];
    for (int i = 0; i < 4; i++)
        for (int j = 0; j < 4; j++) acc[i][j] = (floatx4){0.f, 0.f, 0.f, 0.f};

    // staging: thread -> (row sr 0..63 within 64-row chunk, granule sg 0..7)
    const int sr = tid >> 3;
    const int sg = tid & 7;
    const int scol = (sg ^ (sr & 7)) * 8;    // pre-swizzled global k-offset
    const int rx = qm & 7;                   // read-side granule XOR

    // prologue: stage K-tile 0 into buffer 0
    for (int c = 0; c < 2; c++)
        gl2lds16(A + (m0 + c * 64 + sr) * K + scol, smem + c * 4096 + tid * 8);
    for (int c = 0; c < 4; c++)
        gl2lds16(Bt + (n0 + c * 64 + sr) * K + scol,
                 smem + 8192 + c * 4096 + tid * 8);
    __syncthreads();

    const int nT = K >> 6;
    for (int t = 0; t < nT; ++t) {
        const u16* lA = smem + (t & 1) * 24576;
        const u16* lB = lA + 8192;
        // prefetch next K-tile into the other buffer (its last reader was
        // iteration t-1, protected by that iteration's end barrier).
        if (t + 1 < nT) {
            u16* nb = smem + ((t + 1) & 1) * 24576;
            const int k1 = (t + 1) << 6;
            for (int c = 0; c < 2; c++)
                gl2lds16(A + (m0 + c * 64 + sr) * K + k1 + scol,
                         nb + c * 4096 + tid * 8);
            for (int c = 0; c < 4; c++)
                gl2lds16(Bt + (n0 + c * 64 + sr) * K + k1 + scol,
                         nb + 8192 + c * 4096 + tid * 8);
        }
#pragma unroll
        for (int s = 0; s < 2; s++) {
            short8 af[4], bf[4];
#pragma unroll
            for (int mr = 0; mr < 4; mr++)
                af[mr] = *(const short8*)
                    &lA[(wm * 64 + mr * 16 + qm) * 64 + (((s * 4 + qd) ^ rx) * 8)];
#pragma unroll
            for (int nr = 0; nr < 4; nr++)
                bf[nr] = *(const short8*)
                    &lB[(wn * 64 + nr * 16 + qm) * 64 + (((s * 4 + qd) ^ rx) * 8)];
#pragma unroll
            for (int mr = 0; mr < 4; mr++)
#pragma unroll
                for (int nr = 0; nr < 4; nr++)
                    acc[mr][nr] = __builtin_amdgcn_mfma_f32_16x16x32_bf16(
                        af[mr], bf[nr], acc[mr][nr], 0, 0, 0);
        }
        __syncthreads();
    }

    if (MODE == 0) {
        // Two-half LDS-staged epilogue (lC aliases smem, stride 264 u16);
        // every 128B output line written once, fully. part = n0>>10 is
        // block-uniform (256-wide tile, 1024-aligned part boundaries).
        const float qscale = __expf(temp_f[0]) * 1.44269504089f;
        const int part = (int)(n0 >> 10);
        const float sc = (part == 0) ? qscale : 1.0f;
        u16* lC = smem;
        for (int half = 0; half < 2; half++) {
            __syncthreads();
            if (wm == half) {
                for (int nr = 0; nr < 4; nr++) {
                    int col = wn * 64 + nr * 16 + qm;
                    for (int mr = 0; mr < 4; mr++)
                        for (int r = 0; r < 4; r++)
                            lC[(mr * 16 + qd * 4 + r) * 264 + col] =
                                f2bf(acc[mr][nr][r] * sc);
                }
            }
            __syncthreads();
            const long mb = m0 + half * 64;
            const long bb = mb >> 11;          // batch (64 rows same batch)
            const int  nb = (int)(mb & 2047);  // first token of this half
            for (int i = 0; i < 4; i++) {
                int row = (tid >> 5) + i * 16;     // 0..63
                int c = (tid & 31) * 8;            // col, 8-aligned, 0..248
                long ngc = n0 + c;
                int pt = (int)(ngc >> 10);
                int rem = (int)(ngc & 1023);
                int hh = rem >> 6, dh = rem & 63;
                long idx = ((bb * H_ + hh) * N_ + (nb + row)) * DH_ + dh;
                short8 vv = *(const short8*)&lC[row * 264 + c];
                u16* dst = (pt == 0) ? out0 : (pt == 1) ? out1 : out2;
                *(short8*)&dst[idx] = vv;
            }
        }
    } else {
        // Two-half fp32 epilogue (lCf aliases smem, stride 260 floats =
        // 66.5KB <= 96KB), cooperative full-line nt stores (d_out never
        // re-read by any later kernel).
        const int f = flag[0];
        float* lCf = (float*)smem;
        for (int half = 0; half < 2; half++) {
            __syncthreads();
            if (wm == half) {
                for (int nr = 0; nr < 4; nr++) {
                    long ng = n0 + wn * 64 + nr * 16 + qm;
                    float bv = bias[ng];
                    for (int mr = 0; mr < 4; mr++)
                        for (int r = 0; r < 4; r++)
                            lCf[(mr * 16 + qd * 4 + r) * 260 + wn * 64 + nr * 16 + qm] =
                                acc[mr][nr][r] + bv;
                }
            }
            __syncthreads();
            if (f) {
                for (int i = 0; i < 4; i++) {
                    int row = (tid >> 5) + i * 16;   // 0..63
                    int c = (tid & 31) * 8;          // col, 8-aligned
                    long m = m0 + half * 64 + row;
                    u16 tmp[8];
                    for (int j = 0; j < 8; j++) tmp[j] = f2bf(lCf[row * 260 + c + j]);
                    __builtin_nontemporal_store(*(const short8*)tmp,
                        (short8*)&((u16*)outv)[m * N + n0 + c]);
                }
            } else {
                for (int i = 0; i < 8; i++) {
                    int row = (tid >> 6) + i * 8;    // 0..63
                    int c = (tid & 63) * 4;          // col, 4-aligned fp32
                    long m = m0 + half * 64 + row;
                    floatx4 vv = *(const floatx4*)&lCf[row * 260 + c];
                    __builtin_nontemporal_store(vv,
                        (floatx4*)&((float*)outv)[m * N + n0 + c]);
                }
            }
        }
    }
}

// ---------------- flash attention, R11-exact -------------------------------
// grid = (8, 64) remapped XCD-aware; 512 blocks x 4 waves (2 blocks/CU).
// Wave w owns qrows qbase..+63 as 2 groups of 32; each K/V fragment read
// feeds both groups' MFMAs. K/V double-buffered. S^T = K*Q^T via
// mfma_32x32x16; P->bf16 cvt_pk; permlane32_swap builds PV B-frag; 1/l
// lane-local. Output LDS-staged full-line stores.
__global__ __launch_bounds__(256) void attn_full(
    const u16* __restrict__ q_ws, const u16* __restrict__ k_ws,
    const u16* __restrict__ vt_ws, u16* __restrict__ out) {
    __shared__ __align__(16) u16 lbuf[2 * 2 * 64 * 64];  // 32 KiB
    const int tid = threadIdx.x, lane = tid & 63, w = tid >> 6;
    const int ln = lane & 31, h = lane >> 5;

    int linear = blockIdx.y * 8 + blockIdx.x;
    int bh = (linear & 7) * 8 + ((linear >> 6) & 7);
    int q0 = ((linear >> 3) & 7) * 256;
    const int b = bh >> 4, hd = bh & 15;

    const u16* Q = q_ws + (long)bh * N_ * DH_;
    const u16* Kp = k_ws + (long)bh * N_ * DH_;
    const u16* Vt = vt_ws + (long)bh * DH_ * N_;

    const int qbase = q0 + w * 64;

    short8 qa[2][4];
#pragma unroll
    for (int g = 0; g < 2; g++)
#pragma unroll
        for (int c = 0; c < 4; c++)
            qa[g][c] = *(const short8*)
                &Q[(long)(qbase + g * 32 + ln) * DH_ + c * 16 + h * 8];

    floatx16 accO[2][2];
#pragma unroll
    for (int i = 0; i < 16; i++) {
        accO[0][0][i] = 0.f; accO[0][1][i] = 0.f;
        accO[1][0][i] = 0.f; accO[1][1][i] = 0.f;
    }
    float lacc[2] = {0.f, 0.f};

    const int srow = lane >> 3;
    const int scol = ((lane & 7) ^ srow) * 8;
    const int rsw = (ln & 7);

    {
        u16* nK = lbuf;
        u16* nV = lbuf + 4096;
        for (int i = 0; i < 2; i++) {
            int c = w + i * 4;
            gl2lds16(Kp + (long)(c * 8 + srow) * DH_ + scol, nK + c * 512);
            gl2lds16(Vt + (long)(c * 8 + srow) * N_ + scol, nV + c * 512);
        }
    }
    __syncthreads();

    for (int t = 0; t < 32; t++) {
        const int k0 = t * 64;
        const u16* lK = lbuf + (t & 1) * 8192;
        const u16* lV = lK + 4096;
        if (t < 31) {
            u16* nK = lbuf + ((t + 1) & 1) * 8192;
            u16* nV = nK + 4096;
            for (int i = 0; i < 2; i++) {
                int c = w + i * 4;
                gl2lds16(Kp + (long)(k0 + 64 + c * 8 + srow) * DH_ + scol,
                         nK + c * 512);
                gl2lds16(Vt + (long)(c * 8 + srow) * N_ + k0 + 64 + scol,
                         nV + c * 512);
            }
        }

#pragma unroll
        for (int kt = 0; kt < 2; kt++) {
            floatx16 accS[2];
#pragma unroll
            for (int i = 0; i < 16; i++) { accS[0][i] = 0.f; accS[1][i] = 0.f; }
#pragma unroll
            for (int c = 0; c < 4; c++) {
                short8 kf = *(const short8*)
                    &lK[(kt * 32 + ln) * 64 + ((c * 2 + h) ^ rsw) * 8];
                accS[0] = __builtin_amdgcn_mfma_f32_32x32x16_bf16(
                    kf, qa[0][c], accS[0], 0, 0, 0);
                accS[1] = __builtin_amdgcn_mfma_f32_32x32x16_bf16(
                    kf, qa[1][c], accS[1], 0, 0, 0);
            }
#pragma unroll
            for (int g = 0; g < 2; g++) {
#pragma unroll
                for (int r = 0; r < 16; r++)
                    accS[g][r] = fast_exp2(accS[g][r]);
                if ((qbase + g * 32) == (k0 + kt * 32)) {
#pragma unroll
                    for (int r = 0; r < 16; r++) {
                        int kk = (r & 3) + 8 * (r >> 2) + 4 * h;
                        if (kk == ln) accS[g][r] = 0.f;
                    }
                }
                float rs = (((accS[g][0] + accS[g][1]) + (accS[g][2] + accS[g][3]))
                          + ((accS[g][4] + accS[g][5]) + (accS[g][6] + accS[g][7])))
                         + (((accS[g][8] + accS[g][9]) + (accS[g][10] + accS[g][11]))
                          + ((accS[g][12] + accS[g][13]) + (accS[g][14] + accS[g][15])));
                lacc[g] += rs;
            }
#pragma unroll
            for (int ch = 0; ch < 2; ch++) {
                const int rb = ch * 8;
                short8 pfv[2];
#pragma unroll
                for (int g = 0; g < 2; g++) {
                    unsigned d01 = cvtpk_bf16(accS[g][rb + 0], accS[g][rb + 1]);
                    unsigned d23 = cvtpk_bf16(accS[g][rb + 2], accS[g][rb + 3]);
                    unsigned d45 = cvtpk_bf16(accS[g][rb + 4], accS[g][rb + 5]);
                    unsigned d67 = cvtpk_bf16(accS[g][rb + 6], accS[g][rb + 7]);
                    uint2v s1 = __builtin_amdgcn_permlane32_swap(d01, d45, false, false);
                    uint2v s2 = __builtin_amdgcn_permlane32_swap(d23, d67, false, false);
                    union { unsigned u[4]; short8 v; } pf;
                    pf.u[0] = s1[0]; pf.u[1] = s2[0]; pf.u[2] = s1[1]; pf.u[3] = s2[1];
                    pfv[g] = pf.v;
                }
                const int cc = kt * 2 + ch;
#pragma unroll
                for (int dt = 0; dt < 2; dt++) {
                    short8 vf = *(const short8*)
                        &lV[(dt * 32 + ln) * 64 + ((cc * 2 + h) ^ rsw) * 8];
                    accO[0][dt] = __builtin_amdgcn_mfma_f32_32x32x16_bf16(
                        vf, pfv[0], accO[0][dt], 0, 0, 0);
                    accO[1][dt] = __builtin_amdgcn_mfma_f32_32x32x16_bf16(
                        vf, pfv[1], accO[1][dt], 0, 0, 0);
                }
            }
        }
        __syncthreads();
    }

#pragma unroll
    for (int g = 0; g < 2; g++) {
        float s = lacc[g];
        s += __shfl_xor(s, 32, 64);
        const float inv = 1.f / s;
        u16* stg = (u16*)((char*)lbuf + w * 8192 + g * 4096);
#pragma unroll
        for (int dt = 0; dt < 2; dt++)
#pragma unroll
            for (int q2 = 0; q2 < 4; q2++) {
                union { unsigned u[2]; unsigned long long ull; } ee;
                ee.u[0] = cvtpk_bf16(accO[g][dt][q2 * 4 + 0] * inv,
                                     accO[g][dt][q2 * 4 + 1] * inv);
                ee.u[1] = cvtpk_bf16(accO[g][dt][q2 * 4 + 2] * inv,
                                     accO[g][dt][q2 * 4 + 3] * inv);
                int G = dt * 4 + q2;
                *(unsigned long long*)
                    &stg[ln * 64 + ((G ^ rsw) * 8) + h * 4] = ee.ull;
            }
    }
    __syncthreads();
#pragma unroll
    for (int p = 0; p < 8; p++) {
        int R = p * 32 + (tid >> 3);
        int G = tid & 7;
        const u16* src = (const u16*)((char*)lbuf + (R >> 6) * 8192
                          + ((R >> 5) & 1) * 4096
                          + (R & 31) * 128 + ((G ^ (R & 7)) * 16));
        short8 vv = *(const short8*)src;
        *(short8*)&out[((long)(b * N_ + q0 + R)) * INNER_ + hd * DH_ + G * 8] = vv;
    }
}

extern "C" void kernel_launch(void* const* d_in, const int* in_sizes, int n_in,
                              void* d_out, int out_size, void* d_ws, size_t ws_size,
                              hipStream_t stream) {
    const void* x    = d_in[0];
    const void* Wqkv = d_in[1];
    const void* Wout = d_in[2];
    const void* bout = d_in[3];
    const void* temp = d_in[4];

    char* base = (char*)d_ws;
    int*   flag    = (int*)base;
    float* temp_f  = (float*)(base + 16);
    float* bias_f  = (float*)(base + 32);
    u16* xb      = (u16*)(base + 8192);
    u16* Wqkv_t  = xb + (long)M_ * D_;
    u16* Wout_t  = Wqkv_t + 3072 * 1024;
    u16* q_ws    = Wout_t + 1024 * 1024;
    u16* k_ws    = q_ws + (long)B_ * H_ * N_ * DH_;
    u16* vt_ws   = k_ws + (long)B_ * H_ * N_ * DH_;
    u16* attn_out = vt_ws + (long)B_ * H_ * N_ * DH_;
    u16* v_nat   = attn_out;  // alias: dead until attn_full writes it

    dim3 blk(256);
    detect_prep<<<1, blk, 0, stream>>>((const u16*)x, flag, bout, temp,
                                       bias_f, temp_f);
    prep_inputs<<<dim3(4096 + 3072 + 1024), blk, 0, stream>>>(
        x, xb, Wqkv, Wqkv_t, Wout, Wout_t, flag);
    gemm_bt<0><<<dim3(M_ / 128, 3 * INNER_ / 256), dim3(512), 0, stream>>>(
        xb, Wqkv_t, M_, 3 * INNER_, D_, q_ws, k_ws, v_nat, nullptr, nullptr,
        flag, temp_f);
    transpose_v<<<dim3(DH_ / 32, N_ / 32, B_ * H_), blk, 0, stream>>>(
        v_nat, vt_ws);
    attn_full<<<dim3(8, 64), blk, 0, stream>>>(
        q_ws, k_ws, vt_ws, attn_out);
    gemm_bt<1><<<dim3(M_ / 128, D_ / 256), dim3(512), 0, stream>>>(
        attn_out, Wout_t, M_, D_, INNER_, nullptr, nullptr, nullptr, d_out,
        bias_f, flag, temp_f);
}